// Round 5
// baseline (41.525 us; speedup 1.0000x reference)
//
#include <hip/hip_runtime.h>
#include <hip/hip_bf16.h>
#include <stdint.h>

// SVR polynomial-kernel prediction:
//   out[m] = sum_n alpha[n] * (1 + x_p[m].X[n])^4 + b
// m=16384, n=8192, d=64, all fp32 in/out.
// bf16 MFMA 16x16x32, both operands row-major [*,64] ("B^T" layout).
// R5: split MFMA-issue from epilogue (all 16 MFMAs back-to-back into
//     acc[8], then all epilogues) to kill in-order MFMA->VALU stalls;
//     acc initialized to alpha^(1/4) so epilogue is t2=t*t; fma (2 ops).
//     Keep: MT=8, NSPLIT=32, rolled nt loop (#pragma unroll 1 -- R2 lesson),
//     X prescaled by alpha^(1/4).

typedef __attribute__((ext_vector_type(8))) short bf16x8;
typedef __attribute__((ext_vector_type(4))) float f32x4;

#define MM 16384
#define NN 8192
#define DD 64
#define NSPLIT 32
#define NC (NN / NSPLIT)   // 256 n per wave
#define MT 8               // 8 m-tiles of 16 rows => 128 rows per wave
#define MROWS 128
#define NTILES (NC / 16)   // 16 iterations

__device__ __forceinline__ unsigned short f2bf(float f) {
    uint32_t u = __float_as_uint(f);
    uint32_t r = (u + 0x7FFFu + ((u >> 16) & 1u)) >> 16;  // round-to-nearest-even
    return (unsigned short)r;
}

// xp -> bf16; X -> bf16 prescaled by alpha[n]^(1/4); alpha4f[n] = alpha[n]^(1/4)
__global__ void convert_kernel(const float* __restrict__ xp,
                               const float* __restrict__ X,
                               const float* __restrict__ alpha,
                               unsigned short* __restrict__ xbf,
                               unsigned short* __restrict__ Xbf,
                               float* __restrict__ alpha4f) {
    const int xp4 = MM * DD / 4;          // 262144 float4s
    const int X4 = NN * DD / 4;           // 131072 float4s
    const int tot4 = xp4 + X4;
    int tid0 = blockIdx.x * blockDim.x + threadIdx.x;
    int stride = gridDim.x * blockDim.x;
    for (int i = tid0; i < tot4; i += stride) {
        if (i < xp4) {
            float4 v = ((const float4*)xp)[i];
            ushort4 o;
            o.x = f2bf(v.x); o.y = f2bf(v.y); o.z = f2bf(v.z); o.w = f2bf(v.w);
            *(ushort4*)(xbf + (size_t)i * 4) = o;
        } else {
            int off = i - xp4;
            int row = off >> 4;           // 16 float4 per 64-elem row
            float a4 = sqrtf(sqrtf(alpha[row]));
            float4 v = ((const float4*)X)[off];
            ushort4 o;
            o.x = f2bf(v.x * a4); o.y = f2bf(v.y * a4);
            o.z = f2bf(v.z * a4); o.w = f2bf(v.w * a4);
            *(ushort4*)(Xbf + (size_t)off * 4) = o;
        }
    }
    if (tid0 < NN) alpha4f[tid0] = sqrtf(sqrtf(alpha[tid0]));
}

__global__ __launch_bounds__(256) void svr_main(
        const unsigned short* __restrict__ xbf,
        const unsigned short* __restrict__ Xbf,
        const float* __restrict__ alpha4f,
        float* __restrict__ partials) {
    const int lane = threadIdx.x & 63;
    const int gw = (blockIdx.x << 2) + (threadIdx.x >> 6);  // global wave id
    const int mgroup = gw >> 5;            // 0..127  (gw / NSPLIT)
    const int nchunk = gw & (NSPLIT - 1);  // 0..31

    const int r = lane & 15;   // A row within tile / B col within tile
    const int g = lane >> 4;   // k-block selector (k = g*8 + j)

    // Load A fragments for 8 m-tiles (held in registers for whole sweep)
    bf16x8 a[MT][2];
#pragma unroll
    for (int mt = 0; mt < MT; ++mt) {
        const unsigned short* p =
            xbf + (size_t)(mgroup * MROWS + mt * 16 + r) * DD + g * 8;
        a[mt][0] = *(const bf16x8*)p;          // k = 0..31 slice
        a[mt][1] = *(const bf16x8*)(p + 32);   // k = 32..63 slice
    }

    f32x4 red[MT];
#pragma unroll
    for (int mt = 0; mt < MT; ++mt) red[mt] = (f32x4){0.f, 0.f, 0.f, 0.f};

    const int nbase = nchunk * NC;

    // 2-stage pipeline, rolled loop (do NOT unroll: VGPR blowup, see R2)
    const unsigned short* q0 = Xbf + (size_t)(nbase + r) * DD + g * 8;
    bf16x8 b0 = *(const bf16x8*)q0;
    bf16x8 b1 = *(const bf16x8*)(q0 + 32);
    float av4 = alpha4f[nbase + r];

#pragma unroll 1
    for (int nt = 0; nt < NTILES; ++nt) {
        bf16x8 b0n, b1n;
        float av4n;
        if (nt + 1 < NTILES) {
            const unsigned short* q =
                Xbf + (size_t)(nbase + (nt + 1) * 16 + r) * DD + g * 8;
            b0n = *(const bf16x8*)q;
            b1n = *(const bf16x8*)(q + 32);
            av4n = alpha4f[nbase + (nt + 1) * 16 + r];
        }
        // Phase 1: issue all MFMAs back-to-back (8 independent chains).
        // acc starts at a4 so that t = a4 + a4*(x.X) = a4*(1 + x.X).
        f32x4 acc[MT];
#pragma unroll
        for (int mt = 0; mt < MT; ++mt)
            acc[mt] = (f32x4){av4, av4, av4, av4};
#pragma unroll
        for (int mt = 0; mt < MT; ++mt)
            acc[mt] = __builtin_amdgcn_mfma_f32_16x16x32_bf16(a[mt][0], b0, acc[mt], 0, 0, 0);
#pragma unroll
        for (int mt = 0; mt < MT; ++mt)
            acc[mt] = __builtin_amdgcn_mfma_f32_16x16x32_bf16(a[mt][1], b1, acc[mt], 0, 0, 0);
        // Phase 2: epilogue. red += t^4  (t already includes a4 scaling)
#pragma unroll
        for (int mt = 0; mt < MT; ++mt) {
#pragma unroll
            for (int i = 0; i < 4; ++i) {
                float t = acc[mt][i];
                float t2 = t * t;
                red[mt][i] = fmaf(t2, t2, red[mt][i]);
            }
        }
        if (nt + 1 < NTILES) { b0 = b0n; b1 = b1n; av4 = av4n; }
    }

    // Reduce across the 16 column-lanes (lane&15); rows live at (g*4+i).
#pragma unroll
    for (int mt = 0; mt < MT; ++mt) {
#pragma unroll
        for (int i = 0; i < 4; ++i) {
            float v = red[mt][i];
            v += __shfl_xor(v, 1);
            v += __shfl_xor(v, 2);
            v += __shfl_xor(v, 4);
            v += __shfl_xor(v, 8);
            red[mt][i] = v;
        }
    }
    if (r == 0) {
#pragma unroll
        for (int mt = 0; mt < MT; ++mt) {
#pragma unroll
            for (int i = 0; i < 4; ++i) {
                int row = mgroup * MROWS + mt * 16 + g * 4 + i;
                partials[(size_t)nchunk * MM + row] = red[mt][i];
            }
        }
    }
}

__global__ void finalize_kernel(const float* __restrict__ partials,
                                const float* __restrict__ bbias,
                                float* __restrict__ out) {
    int m = blockIdx.x * blockDim.x + threadIdx.x;
    if (m < MM) {
        float s = bbias[0];
#pragma unroll
        for (int c = 0; c < NSPLIT; ++c) s += partials[(size_t)c * MM + m];
        out[m] = s;
    }
}

extern "C" void kernel_launch(void* const* d_in, const int* in_sizes, int n_in,
                              void* d_out, int out_size, void* d_ws, size_t ws_size,
                              hipStream_t stream) {
    const float* xp    = (const float*)d_in[0];
    const float* X     = (const float*)d_in[1];
    const float* alpha = (const float*)d_in[2];
    const float* b     = (const float*)d_in[3];
    float* out = (float*)d_out;

    // ws layout: xbf 2MB | Xbf 1MB | alpha4f 32KB | partials 32*16384*4 = 2MB
    unsigned short* xbf = (unsigned short*)d_ws;
    unsigned short* Xbf = xbf + (size_t)MM * DD;
    float* alpha4f = (float*)(Xbf + (size_t)NN * DD);
    float* partials = alpha4f + NN;

    hipLaunchKernelGGL(convert_kernel, dim3(1024), dim3(256), 0, stream,
                       xp, X, alpha, xbf, Xbf, alpha4f);

    const int waves = (MM / MROWS) * NSPLIT;  // 4096 waves
    hipLaunchKernelGGL(svr_main, dim3(waves / 4), dim3(256), 0, stream,
                       xbf, Xbf, alpha4f, partials);

    hipLaunchKernelGGL(finalize_kernel, dim3(MM / 256), dim3(256), 0, stream,
                       partials, b, out);
}

// Round 6
// 36.038 us; speedup vs baseline: 1.1523x; 1.1523x over previous
//
#include <hip/hip_runtime.h>
#include <hip/hip_bf16.h>
#include <stdint.h>

// SVR polynomial-kernel prediction:
//   out[m] = sum_n alpha[n] * (1 + x_p[m].X[n])^4 + b
// m=16384, n=8192, d=64, all fp32 in/out.
// R6: LDS-staged 2-phase structure (attn-QK^T shape, per m214 ladder):
//   - block = 256 thr (4 waves), 128 m-rows/block, A (x_p) in registers
//   - X staged per 64-col chunk (8KB) into dbuf LDS via global_load_lds(16B)
//   - X stored in global PRE-SWIZZLED (slot ^= row&7 per 16B slot) so the
//     LDS copy is linear (rule 21) and ds_read_b128 is conflict-free
//   - alpha folded: Xs rows prescaled by alpha^(1/4); MFMA C-init = alpha^(1/4)
//     => acc = a4*(1+x.X); epilogue t2=t*t; red=fma(t2,t2,red)  (2 VALU/elem)
//   - 16x16x32 bf16 MFMA (known-good layouts from R1)

typedef __attribute__((ext_vector_type(8))) short bf16x8;
typedef __attribute__((ext_vector_type(8))) unsigned short ushort8;
typedef __attribute__((ext_vector_type(4))) float f32x4;

#define MM 16384
#define NN 8192
#define DD 64
#define NSPLIT 16          // n-splits -> partial slices
#define CHUNK 64           // n-cols per LDS chunk
#define CHUNKS_PER_BLK 8   // 8192 / (16*64)
#define BM 128             // m-rows per block

__device__ __forceinline__ unsigned short f2bf(float f) {
    uint32_t u = __float_as_uint(f);
    uint32_t r = (u + 0x7FFFu + ((u >> 16) & 1u)) >> 16;  // RNE
    return (unsigned short)r;
}

__device__ __forceinline__ void gll16(const void* g, void* l) {
    __builtin_amdgcn_global_load_lds(
        (const __attribute__((address_space(1))) unsigned int*)g,
        (__attribute__((address_space(3))) unsigned int*)l, 16, 0, 0);
}

// xp -> xbf linear row-major [16384][64] bf16.
// X  -> Xs swizzled: element (n,k) at shorts:
//   (n>>6)*4096 + (n&63)*64 + ((k>>3) ^ (n&7))*8 + (k&7),  prescaled by a4[n].
// alpha4f[n] = alpha[n]^(1/4).
__global__ void convert_kernel(const float* __restrict__ xp,
                               const float* __restrict__ X,
                               const float* __restrict__ alpha,
                               unsigned short* __restrict__ xbf,
                               unsigned short* __restrict__ Xs,
                               float* __restrict__ alpha4f) {
    const int xp4 = MM * DD / 4;          // 262144 float4 units
    const int xu = NN * DD / 8;           // 65536 16B units
    const int tot = xp4 + xu;
    int tid0 = blockIdx.x * blockDim.x + threadIdx.x;
    if (tid0 < NN) alpha4f[tid0] = sqrtf(sqrtf(alpha[tid0]));
    int stride = gridDim.x * blockDim.x;
    for (int i = tid0; i < tot; i += stride) {
        if (i < xp4) {
            float4 v = ((const float4*)xp)[i];
            ushort4 o;
            o.x = f2bf(v.x); o.y = f2bf(v.y); o.z = f2bf(v.z); o.w = f2bf(v.w);
            *(ushort4*)(xbf + (size_t)i * 4) = o;
        } else {
            int u = i - xp4;
            int n = u >> 3;
            int slot = u & 7;
            float a4 = sqrtf(sqrtf(alpha[n]));
            float4 va = ((const float4*)X)[n * 16 + slot * 2];
            float4 vb = ((const float4*)X)[n * 16 + slot * 2 + 1];
            ushort8 o;
            o[0] = f2bf(va.x * a4); o[1] = f2bf(va.y * a4);
            o[2] = f2bf(va.z * a4); o[3] = f2bf(va.w * a4);
            o[4] = f2bf(vb.x * a4); o[5] = f2bf(vb.y * a4);
            o[6] = f2bf(vb.z * a4); o[7] = f2bf(vb.w * a4);
            size_t dst = (size_t)(n >> 6) * 4096 + (n & 63) * 64
                       + ((slot ^ (n & 7)) * 8);
            *(ushort8*)(Xs + dst) = o;
        }
    }
}

__global__ __launch_bounds__(256) void svr_main(
        const unsigned short* __restrict__ xbf,
        const unsigned short* __restrict__ Xs,
        const float* __restrict__ alpha4f,
        float* __restrict__ partials) {
    __shared__ char smem[16384];          // 2 x 8KB chunk buffers
    const int tid  = threadIdx.x;
    const int lane = tid & 63;
    const int w    = tid >> 6;            // wave 0..3, owns rows [w*32, w*32+32)
    const int r    = lane & 15;           // row-in-tile / col-in-tile
    const int g    = lane >> 4;           // k-slice selector
    const int mgroup = blockIdx.x >> 4;   // 0..127
    const int ns     = blockIdx.x & 15;   // 0..15

    // A fragments: 2 m-tiles x 2 k-slices, regs for whole kernel
    bf16x8 a[2][2];
#pragma unroll
    for (int mt = 0; mt < 2; ++mt)
#pragma unroll
        for (int ks = 0; ks < 2; ++ks)
            a[mt][ks] = *(const bf16x8*)(
                xbf + (size_t)(mgroup * BM + w * 32 + mt * 16 + r) * DD
                    + ks * 32 + g * 8);

    f32x4 red[2];
#pragma unroll
    for (int mt = 0; mt < 2; ++mt) red[mt] = (f32x4){0.f, 0.f, 0.f, 0.f};

    const int chunk0 = ns * CHUNKS_PER_BLK;

    // prologue: stage chunk0 into buf0 (linear copy; Xs already swizzled)
    {
        const char* gs = (const char*)Xs + (size_t)chunk0 * 8192 + tid * 16;
        char* lb = smem + w * 1024;       // wave-uniform base; +lane*16 implicit
        gll16(gs, lb);
        gll16(gs + 4096, lb + 4096);
    }
    __syncthreads();

    int cur = 0;
#pragma unroll 1
    for (int c = 0; c < CHUNKS_PER_BLK; ++c) {
        if (c + 1 < CHUNKS_PER_BLK) {      // stage next chunk into other buffer
            const char* gs = (const char*)Xs
                           + (size_t)(chunk0 + c + 1) * 8192 + tid * 16;
            char* lb = smem + (cur ^ 1) * 8192 + w * 1024;
            gll16(gs, lb);
            gll16(gs + 4096, lb + 4096);
        }
        const int n0 = (chunk0 + c) * CHUNK;
        // alpha^(1/4) for this lane's 4 columns (one per n-tile)
        float av4[4];
#pragma unroll
        for (int nt = 0; nt < 4; ++nt)
            av4[nt] = alpha4f[n0 + nt * 16 + r];
        // B fragments from swizzled LDS: rr = nt*16+r, slot = (bh*4+g)^(rr&7)
        bf16x8 b[4][2];
#pragma unroll
        for (int nt = 0; nt < 4; ++nt) {
            const int rr = nt * 16 + r;
            const char* rowp = smem + cur * 8192 + rr * 128;
#pragma unroll
            for (int bh = 0; bh < 2; ++bh) {
                const int slot = (bh * 4 + g) ^ (rr & 7);
                b[nt][bh] = *(const bf16x8*)(rowp + slot * 16);
            }
        }
        // acc C-init = a4 so acc_final = a4*(1 + x.X)
        f32x4 acc[2][4];
#pragma unroll
        for (int mt = 0; mt < 2; ++mt)
#pragma unroll
            for (int nt = 0; nt < 4; ++nt)
                acc[mt][nt] = (f32x4){av4[nt], av4[nt], av4[nt], av4[nt]};
#pragma unroll
        for (int bh = 0; bh < 2; ++bh)
#pragma unroll
            for (int nt = 0; nt < 4; ++nt)
#pragma unroll
                for (int mt = 0; mt < 2; ++mt)
                    acc[mt][nt] = __builtin_amdgcn_mfma_f32_16x16x32_bf16(
                        a[mt][bh], b[nt][bh], acc[mt][nt], 0, 0, 0);
        // epilogue: red += t^4
#pragma unroll
        for (int mt = 0; mt < 2; ++mt)
#pragma unroll
            for (int nt = 0; nt < 4; ++nt)
#pragma unroll
                for (int i = 0; i < 4; ++i) {
                    float t = acc[mt][nt][i];
                    float t2 = t * t;
                    red[mt][i] = fmaf(t2, t2, red[mt][i]);
                }
        __syncthreads();
        cur ^= 1;
    }

    // reduce across the 16 column-lanes (r); rows live at g*4+i per m-tile
#pragma unroll
    for (int mt = 0; mt < 2; ++mt)
#pragma unroll
        for (int i = 0; i < 4; ++i) {
            float v = red[mt][i];
            v += __shfl_xor(v, 1);
            v += __shfl_xor(v, 2);
            v += __shfl_xor(v, 4);
            v += __shfl_xor(v, 8);
            red[mt][i] = v;
        }
    if (r == 0) {
#pragma unroll
        for (int mt = 0; mt < 2; ++mt)
#pragma unroll
            for (int i = 0; i < 4; ++i) {
                int row = mgroup * BM + w * 32 + mt * 16 + g * 4 + i;
                partials[(size_t)ns * MM + row] = red[mt][i];
            }
    }
}

__global__ void finalize_kernel(const float* __restrict__ partials,
                                const float* __restrict__ bbias,
                                float* __restrict__ out) {
    int m = blockIdx.x * blockDim.x + threadIdx.x;
    if (m < MM) {
        float s = bbias[0];
#pragma unroll
        for (int c = 0; c < NSPLIT; ++c) s += partials[(size_t)c * MM + m];
        out[m] = s;
    }
}

extern "C" void kernel_launch(void* const* d_in, const int* in_sizes, int n_in,
                              void* d_out, int out_size, void* d_ws, size_t ws_size,
                              hipStream_t stream) {
    const float* xp    = (const float*)d_in[0];
    const float* X     = (const float*)d_in[1];
    const float* alpha = (const float*)d_in[2];
    const float* b     = (const float*)d_in[3];
    float* out = (float*)d_out;

    // ws: xbf 2MB | Xs 1MB | alpha4f 32KB | partials 16*16384*4 = 1MB
    unsigned short* xbf = (unsigned short*)d_ws;
    unsigned short* Xs  = xbf + (size_t)MM * DD;
    float* alpha4f = (float*)(Xs + (size_t)NN * DD);
    float* partials = alpha4f + NN;

    hipLaunchKernelGGL(convert_kernel, dim3(1280), dim3(256), 0, stream,
                       xp, X, alpha, xbf, Xs, alpha4f);

    hipLaunchKernelGGL(svr_main, dim3(128 * NSPLIT), dim3(256), 0, stream,
                       xbf, Xs, alpha4f, partials);

    hipLaunchKernelGGL(finalize_kernel, dim3(MM / 256), dim3(256), 0, stream,
                       partials, b, out);
}